// Round 8
// baseline (1518.397 us; speedup 1.0000x reference)
//
#include <hip/hip_runtime.h>
#include <stdint.h>

#define BATCH 512
#define MAXZ 3

// ---- workspace layout (bytes) ----
static const size_t OFF_W2P  = 0;          // 25*128*4 u32
static const size_t OFF_W3P  = 51200;
static const size_t OFF_W4P  = 69632;
static const size_t OFF_FCP  = 88064;
static const size_t OFF_STAT = 219136;     // mean1..4 f32[512] @0/2048/4096/6144; zcnt int[512]@8192; zlist int[512*3]@10240
static const size_t OFF_B1P  = 235520;     // 512*784*16
static const size_t OFF_H2   = 6658048;    // 512*144*128*4 raw counts (float, exact)
static const size_t OFF_B2P  = 44406784;
static const size_t OFF_H3   = 45586432;   // 512*100*128*4
static const size_t OFF_B3P  = 71800832;
static const size_t OFF_H4   = 72620032;   // 512*16*128*4
static const size_t OFF_BXP  = 76814336;
// end ~76.9 MB

// Numerics model (refined r7): np reference conv1 emulates np.einsum's
// f32 sum_of_products_contig_two SSE2 kernel over K=25 (im2col):
//   p_k = round(w_k*x_k)  (mul_ps, no FMA)
//   lane_j = ((((p_j + p_{j+4}) + p_{j+8}) + p_{j+12}) + p_{j+16}) + p_{j+20}
//   acc = (l0+l1)+(l2+l3); acc += p_24   (scalar cleanup last)
// Means are numpy pairwise-f32 (recursion geometry verified). Downstream
// binary layers are exact integer math, insensitive (measured r4==r5==r7).

// product with forced f32 rounding (blocks FMA contraction, zero cost)
__device__ inline float mulr(float a, float b) {
    float t = a * b;
    asm volatile("" : "+v"(t));
    return t;
}

// ---------------- weight packing ----------------
__global__ void pack_conv_w(const float* __restrict__ w, uint32_t* __restrict__ wp, int taps) {
    int idx = blockIdx.x * 256 + threadIdx.x;
    if (idx >= 128 * taps) return;
    int oc = idx / taps, t = idx - oc * taps;
    uint32_t words[4] = {0u, 0u, 0u, 0u};
    for (int ic = 0; ic < 128; ++ic) {
        float v = w[(size_t)(oc * 128 + ic) * taps + t];
        if (v > 0.f) words[ic >> 5] |= 1u << (ic & 31);
    }
#pragma unroll
    for (int k = 0; k < 4; ++k) wp[((size_t)t * 128 + oc) * 4 + k] = words[k];
}

__global__ void pack_fc_w(const float* __restrict__ w, uint32_t* __restrict__ wp) {
    int o = blockIdx.x * 256 + threadIdx.x;
    if (o >= 512) return;
    for (int k = 0; k < 64; ++k) {
        uint32_t bits = 0;
        for (int i = 0; i < 32; ++i)
            bits |= (w[(size_t)o * 2048 + k * 32 + i] > 0.f ? 1u : 0u) << i;
        wp[k * 512 + o] = bits;
    }
}

// conv1 value at (c, p): np.einsum contig_two SSE2 emulation (see header).
__device__ inline float conv1_val(const float* img, const float* wsh, int c, int p) {
    int y = p / 28, xx = p - y * 28;
    const float* ib = &img[y * 32 + xx];
    const float* wr = &wsh[c * 25];
    float pk[25];
#pragma unroll
    for (int ky = 0; ky < 5; ++ky)
#pragma unroll
        for (int kx = 0; kx < 5; ++kx)
            pk[ky * 5 + kx] = mulr(wr[ky * 5 + kx], ib[ky * 32 + kx]);
    float l0 = pk[0], l1 = pk[1], l2 = pk[2], l3 = pk[3];
#pragma unroll
    for (int t = 1; t < 6; ++t) {
        l0 += pk[4 * t + 0];
        l1 += pk[4 * t + 1];
        l2 += pk[4 * t + 2];
        l3 += pk[4 * t + 3];
    }
    float acc = (l0 + l1) + (l2 + l3);
    acc += pk[24];
    return acc > 0.f ? acc : 0.f;
}

// ---------------- conv1 mean: numpy-pairwise f32 over [128][784] ----------------
// 100352 halves to 784-blocks; 784 -> 8 leaves at offsets
// [0,96,192,288,392,488,584,680], sizes [96,96,96,104]x2; adjacent-pair tree.
__global__ __launch_bounds__(256) void conv1_mean(
    const float* __restrict__ x, const float* __restrict__ w1,
    float* __restrict__ mean1, int* __restrict__ zcnt) {
    __shared__ float img[32 * 32];
    __shared__ float wsh[128 * 25];
    __shared__ float ls[2048];
    int n = blockIdx.x, tid = threadIdx.x;
    for (int i = tid; i < 1024; i += 256) img[i] = x[(size_t)n * 1024 + i];
    for (int i = tid; i < 3200; i += 256) wsh[i] = w1[i];
    __syncthreads();
    for (int j = 0; j < 4; ++j) {
        int leaf = tid * 4 + j;                  // [0,1024)
        int c = leaf >> 3, sub = leaf & 7;
        int q = sub & 3;
        int off = ((sub >> 2) ? 392 : 0) + q * 96;
        int len = (q == 3) ? 104 : 96;
        float r[8];
#pragma unroll
        for (int k = 0; k < 8; ++k) r[k] = conv1_val(img, wsh, c, off + k);
        for (int i = 8; i + 8 <= len; i += 8)
#pragma unroll
            for (int k = 0; k < 8; ++k) r[k] += conv1_val(img, wsh, c, off + i + k);
        ls[leaf] = ((r[0] + r[1]) + (r[2] + r[3])) + ((r[4] + r[5]) + (r[6] + r[7]));
    }
    __syncthreads();
    int src = 0, cnt = 1024;
    while (cnt > 1) {
        int dst = src + cnt;
        for (int i = tid; i < cnt / 2; i += 256) ls[dst + i] = ls[src + 2 * i] + ls[src + 2 * i + 1];
        __syncthreads();
        src = dst; cnt >>= 1;
    }
    if (tid == 0) { mean1[n] = ls[src] / 100352.0f; zcnt[n] = 0; }
}

// ---------------- conv1 binarize + pack; detect sign(0) ties ----------------
__global__ __launch_bounds__(256) void conv1_bin(
    const float* __restrict__ x, const float* __restrict__ w1,
    const float* __restrict__ mean1, uint32_t* __restrict__ b1p,
    int* __restrict__ zcnt, int* __restrict__ zlist) {
    __shared__ float img[32 * 32];
    __shared__ float wsh[128 * 25];
    int n = blockIdx.x, tid = threadIdx.x;
    for (int i = tid; i < 1024; i += 256) img[i] = x[(size_t)n * 1024 + i];
    for (int i = tid; i < 3200; i += 256) wsh[i] = w1[i];
    __syncthreads();
    float mean = mean1[n];
    for (int p = tid; p < 784; p += 256) {
        uint32_t words[4] = {0u, 0u, 0u, 0u};
        for (int c = 0; c < 128; ++c) {
            float h = conv1_val(img, wsh, c, p);
            if (h > mean) words[c >> 5] |= 1u << (c & 31);
            else if (h == mean) {                 // sign(0) = 0 in reference
                int k = atomicAdd(&zcnt[n], 1);
                if (k < MAXZ) zlist[n * MAXZ + k] = p * 128 + c;
            }
        }
#pragma unroll
        for (int k = 0; k < 4; ++k) b1p[((size_t)n * 784 + p) * 4 + k] = words[k];
    }
}

// ---------------- binary conv (xnor-popcount) + optional pool + zero fixup ----
template <int AH, int AW, int KS, int POOL, int OW, int NPOS>
__global__ __launch_bounds__(256) void bconv_kernel(
    const uint32_t* __restrict__ actg, const uint32_t* __restrict__ wp,
    float* __restrict__ rout, const int* __restrict__ zcnt,
    const int* __restrict__ zlist) {
    __shared__ __align__(16) uint32_t act[AH * AW * 4];
    __shared__ __align__(16) uint32_t wsh[KS * KS * 128 * 4];
    int n = blockIdx.x, tid = threadIdx.x;
    const uint32_t* src = actg + (size_t)n * AH * AW * 4;
    for (int i = tid; i < AH * AW * 4; i += 256) act[i] = src[i];
    for (int i = tid; i < KS * KS * 128 * 4; i += 256) wsh[i] = wp[i];
    __syncthreads();
    int oc = tid & 127, s = tid >> 7;
    const int KTOT = 128 * KS * KS;
    int nz = 0, zy[MAXZ], zx[MAXZ], zc[MAXZ];
    if (zcnt) {
        nz = zcnt[n]; nz = nz > MAXZ ? MAXZ : nz;
        for (int i = 0; i < nz; ++i) {
            int e = zlist[n * MAXZ + i];
            int p = e >> 7; zc[i] = e & 127; zy[i] = p / AW; zx[i] = p - zy[i] * AW;
        }
    }
    for (int pp = s; pp < NPOS; pp += 2) {
        int py = pp / OW, px = pp - py * OW;
        int r;
        if (POOL) {
            int cy = py * 2, cx = px * 2;
            int a0 = 0, a1 = 0, a2 = 0, a3 = 0;
#pragma unroll
            for (int ky = 0; ky < KS; ++ky)
#pragma unroll
                for (int kx = 0; kx < KS; ++kx) {
                    uint4 wv = *(const uint4*)&wsh[((ky * KS + kx) * 128 + oc) * 4];
                    const uint32_t* ab = &act[((cy + ky) * AW + cx + kx) * 4];
                    uint4 v0 = *(const uint4*)(ab);
                    uint4 v1 = *(const uint4*)(ab + 4);
                    uint4 v2 = *(const uint4*)(ab + AW * 4);
                    uint4 v3 = *(const uint4*)(ab + AW * 4 + 4);
                    a0 += __popc(v0.x ^ wv.x) + __popc(v0.y ^ wv.y) + __popc(v0.z ^ wv.z) + __popc(v0.w ^ wv.w);
                    a1 += __popc(v1.x ^ wv.x) + __popc(v1.y ^ wv.y) + __popc(v1.z ^ wv.z) + __popc(v1.w ^ wv.w);
                    a2 += __popc(v2.x ^ wv.x) + __popc(v2.y ^ wv.y) + __popc(v2.z ^ wv.z) + __popc(v2.w ^ wv.w);
                    a3 += __popc(v3.x ^ wv.x) + __popc(v3.y ^ wv.y) + __popc(v3.z ^ wv.z) + __popc(v3.w ^ wv.w);
                }
            int m0 = KTOT - 2 * a0, m1 = KTOT - 2 * a1;
            int m2 = KTOT - 2 * a2, m3 = KTOT - 2 * a3;
            if (nz) {
                for (int i = 0; i < nz; ++i) {
#pragma unroll
                    for (int d = 0; d < 4; ++d) {
                        int oy = cy + (d >> 1), ox = cx + (d & 1);
                        int ky = zy[i] - oy, kx = zx[i] - ox;
                        if (ky >= 0 && ky < KS && kx >= 0 && kx < KS) {
                            int wbit = (wsh[((ky * KS + kx) * 128 + oc) * 4 + (zc[i] >> 5)] >> (zc[i] & 31)) & 1;
                            int adj = wbit ? 1 : -1;   // remove spurious (-1)*W contribution
                            if (d == 0) m0 += adj; else if (d == 1) m1 += adj;
                            else if (d == 2) m2 += adj; else m3 += adj;
                        }
                    }
                }
            }
            r = max(max(m0, m1), max(m2, m3));
        } else {
            int a0 = 0;
#pragma unroll
            for (int ky = 0; ky < KS; ++ky)
#pragma unroll
                for (int kx = 0; kx < KS; ++kx) {
                    uint4 wv = *(const uint4*)&wsh[((ky * KS + kx) * 128 + oc) * 4];
                    uint4 v0 = *(const uint4*)&act[((py + ky) * AW + px + kx) * 4];
                    a0 += __popc(v0.x ^ wv.x) + __popc(v0.y ^ wv.y) + __popc(v0.z ^ wv.z) + __popc(v0.w ^ wv.w);
                }
            r = KTOT - 2 * a0;
        }
        r = r > 0 ? r : 0;
        rout[((size_t)n * NPOS + pp) * 128 + oc] = (float)r;  // integer, lossless
    }
}

// ---------------- numpy-pairwise f32 mean for layers 2/3/4 ----------------
template <int NPOS, int NLEAF, int CHUNK, int L0, int L1>
__global__ __launch_bounds__(256) void npmean_kernel(
    const float* __restrict__ rbuf, const float* __restrict__ alpha,
    float* __restrict__ means) {
    __shared__ float ls[2 * NLEAF];
    int n = blockIdx.x, tid = threadIdx.x;
    const int NTOT = NPOS * 128;
    const float* rb = rbuf + (size_t)n * NTOT;
    if (tid < NLEAF) {
        int j0 = CHUNK * (tid >> 1) + ((tid & 1) ? L0 : 0);
        int len = (tid & 1) ? L1 : L0;
        float r[8];
#pragma unroll
        for (int k = 0; k < 8; ++k) {
            int j = j0 + k;
            int c = j / NPOS, p = j - c * NPOS;
            r[k] = mulr(alpha[c], rb[p * 128 + c]);
        }
        int i = 8;
        int lim = len - (len % 8);
        for (; i < lim; i += 8) {
#pragma unroll
            for (int k = 0; k < 8; ++k) {
                int j = j0 + i + k;
                int c = j / NPOS, p = j - c * NPOS;
                r[k] += mulr(alpha[c], rb[p * 128 + c]);
            }
        }
        float res = ((r[0] + r[1]) + (r[2] + r[3])) + ((r[4] + r[5]) + (r[6] + r[7]));
        for (; i < len; ++i) {
            int j = j0 + i;
            int c = j / NPOS, p = j - c * NPOS;
            res += mulr(alpha[c], rb[p * 128 + c]);
        }
        ls[tid] = res;
    }
    __syncthreads();
    int src = 0, cnt = NLEAF;
    while (cnt > 1) {
        int dst = src + cnt;
        for (int i = tid; i < cnt / 2; i += 256) ls[dst + i] = ls[src + 2 * i] + ls[src + 2 * i + 1];
        __syncthreads();
        src = dst; cnt >>= 1;
    }
    if (tid == 0) means[n] = ls[src] / (float)NTOT;
}

// ---------------- binarize (f32 compare, matching refs) ----------------
__global__ void bin_kernel(const float* __restrict__ rbuf, const float* __restrict__ means,
                           const float* __restrict__ alpha,
                           uint32_t* __restrict__ bp, int npos) {
    int idx = blockIdx.x * 256 + threadIdx.x;
    int total = BATCH * npos * 4;
    if (idx >= total) return;
    int n = idx / (npos * 4);
    int w = idx & 3;
    float mean = means[n];
    const float* hb = rbuf + (size_t)idx * 32;
    uint32_t bits = 0;
#pragma unroll
    for (int i = 0; i < 32; ++i) {
        float v = mulr(alpha[w * 32 + i], hb[i]);
        bits |= (v > mean ? 1u : 0u) << i;
    }
    bp[idx] = bits;
}

__global__ void bin4_kernel(const float* __restrict__ r4, const float* __restrict__ means,
                            const float* __restrict__ alpha,
                            uint32_t* __restrict__ bxp) {
    int idx = blockIdx.x * 256 + threadIdx.x;   // 512*64
    if (idx >= BATCH * 64) return;
    int n = idx >> 6, w = idx & 63;
    float mean = means[n];
    uint32_t bits = 0;
#pragma unroll
    for (int i = 0; i < 32; ++i) {
        int f = w * 32 + i;
        int c = f >> 4, sp = f & 15;
        float v = mulr(alpha[c], r4[((size_t)n * 16 + sp) * 128 + c]);
        bits |= (v > mean ? 1u : 0u) << i;
    }
    bxp[idx] = bits;
}

// ---------------- binary FC ----------------
__global__ __launch_bounds__(256) void fc_kernel(
    const uint32_t* __restrict__ bxp, const uint32_t* __restrict__ fcpT,
    const float* __restrict__ bias, const float* __restrict__ alpha,
    float* __restrict__ out) {
    __shared__ uint32_t bxs[64];
    int n = blockIdx.x, tid = threadIdx.x;
    if (tid < 64) bxs[tid] = bxp[n * 64 + tid];
    __syncthreads();
    for (int o = tid; o < 512; o += 256) {
        int acc = 0;
#pragma unroll
        for (int k = 0; k < 64; ++k) acc += __popc(bxs[k] ^ fcpT[k * 512 + o]);
        float dot = (float)(2048 - 2 * acc);
        out[(size_t)n * 512 + o] = (dot + bias[o]) * alpha[o];
    }
}

extern "C" void kernel_launch(void* const* d_in, const int* in_sizes, int n_in,
                              void* d_out, int out_size, void* d_ws, size_t ws_size,
                              hipStream_t stream) {
    const float* x   = (const float*)d_in[0];
    const float* w1  = (const float*)d_in[1];
    const float* w2  = (const float*)d_in[2];
    const float* a2  = (const float*)d_in[3];
    const float* w3  = (const float*)d_in[4];
    const float* a3  = (const float*)d_in[5];
    const float* w4  = (const float*)d_in[6];
    const float* a4  = (const float*)d_in[7];
    const float* wfc = (const float*)d_in[8];
    const float* bfc = (const float*)d_in[9];
    const float* afc = (const float*)d_in[10];
    float* out = (float*)d_out;
    char* ws = (char*)d_ws;

    uint32_t* w2p = (uint32_t*)(ws + OFF_W2P);
    uint32_t* w3p = (uint32_t*)(ws + OFF_W3P);
    uint32_t* w4p = (uint32_t*)(ws + OFF_W4P);
    uint32_t* fcp = (uint32_t*)(ws + OFF_FCP);
    float*    mean1 = (float*)(ws + OFF_STAT);
    float*    mean2 = (float*)(ws + OFF_STAT + 2048);
    float*    mean3 = (float*)(ws + OFF_STAT + 4096);
    float*    mean4 = (float*)(ws + OFF_STAT + 6144);
    int*      zcnt  = (int*)(ws + OFF_STAT + 8192);
    int*      zlist = (int*)(ws + OFF_STAT + 10240);
    uint32_t* b1p = (uint32_t*)(ws + OFF_B1P);
    float*    h2  = (float*)(ws + OFF_H2);
    uint32_t* b2p = (uint32_t*)(ws + OFF_B2P);
    float*    h3  = (float*)(ws + OFF_H3);
    uint32_t* b3p = (uint32_t*)(ws + OFF_B3P);
    float*    h4  = (float*)(ws + OFF_H4);
    uint32_t* bxp = (uint32_t*)(ws + OFF_BXP);

    pack_conv_w<<<(128 * 25 + 255) / 256, 256, 0, stream>>>(w2, w2p, 25);
    pack_conv_w<<<(128 * 9 + 255) / 256, 256, 0, stream>>>(w3, w3p, 9);
    pack_conv_w<<<(128 * 9 + 255) / 256, 256, 0, stream>>>(w4, w4p, 9);
    pack_fc_w<<<2, 256, 0, stream>>>(wfc, fcp);

    conv1_mean<<<BATCH, 256, 0, stream>>>(x, w1, mean1, zcnt);
    conv1_bin<<<BATCH, 256, 0, stream>>>(x, w1, mean1, b1p, zcnt, zlist);

    bconv_kernel<28, 28, 5, 1, 12, 144><<<BATCH, 256, 0, stream>>>(b1p, w2p, h2, zcnt, zlist);
    npmean_kernel<144, 256, 144, 72, 72><<<BATCH, 256, 0, stream>>>(h2, a2, mean2);
    bin_kernel<<<(BATCH * 144 * 4) / 256, 256, 0, stream>>>(h2, mean2, a2, b2p, 144);

    bconv_kernel<12, 12, 3, 0, 10, 100><<<BATCH, 256, 0, stream>>>(b2p, w3p, h3, nullptr, nullptr);
    npmean_kernel<100, 128, 200, 96, 104><<<BATCH, 256, 0, stream>>>(h3, a3, mean3);
    bin_kernel<<<(BATCH * 100 * 4) / 256, 256, 0, stream>>>(h3, mean3, a3, b3p, 100);

    bconv_kernel<10, 10, 3, 1, 4, 16><<<BATCH, 256, 0, stream>>>(b3p, w4p, h4, nullptr, nullptr);
    npmean_kernel<16, 16, 256, 128, 128><<<BATCH, 256, 0, stream>>>(h4, a4, mean4);
    bin4_kernel<<<(BATCH * 64) / 256, 256, 0, stream>>>(h4, mean4, a4, bxp);

    fc_kernel<<<BATCH, 256, 0, stream>>>(bxp, fcp, bfc, afc, out);
}

// Round 9
// 1034.923 us; speedup vs baseline: 1.4672x; 1.4672x over previous
//
#include <hip/hip_runtime.h>
#include <stdint.h>

#define BATCH 512
#define MAXZ 3

// ---- workspace layout (bytes) ----
static const size_t OFF_W2P  = 0;          // 25*128*4 u32
static const size_t OFF_W3P  = 51200;
static const size_t OFF_W4P  = 69632;
static const size_t OFF_FCP  = 88064;
static const size_t OFF_STAT = 219136;     // mean1..4 f32[512] @0/2048/4096/6144; zcnt int[512]@8192; zlist int[512*3]@10240
static const size_t OFF_B1P  = 235520;     // 512*784*16
static const size_t OFF_H2   = 6658048;    // 512*144*128*4 raw counts (float, exact)
static const size_t OFF_B2P  = 44406784;
static const size_t OFF_H3   = 45586432;   // 512*100*128*4
static const size_t OFF_B3P  = 71800832;
static const size_t OFF_H4   = 72620032;   // 512*16*128*4
static const size_t OFF_BXP  = 76814336;
// end ~76.9 MB

// Numerics model (validated r8, absmax=0): conv1 = np.einsum f32 SSE2 order:
//   p_k = round(w_k*x_k); lane_j = p_j+p_{j+4}+...+p_{j+20} (sequential);
//   acc = (l0+l1)+(l2+l3); acc += p_24.
// Means = numpy pairwise-f32 (leaf geometry verified). r8 used asm-volatile
// barriers -> compiler spilled pk[25] to scratch (VGPR=20, 1.1GB FETCH,
// 455us/pass). Fix: `#pragma clang fp contract(off)` gives identical rounding
// with normal regalloc/scheduling; weights via wave-uniform scalar loads.

// product with forced f32 rounding (legacy helper for small kernels)
__device__ inline float mulr(float a, float b) {
    float t = a * b;
    asm volatile("" : "+v"(t));
    return t;
}

// einsum SSE2-order 25-tap dot + relu, separately-rounded mul/add (no FMA).
__device__ inline float einsum25(const float* __restrict__ patch,
                                 const float* __restrict__ wr) {
#pragma clang fp contract(off)
    float l0 = wr[0] * patch[0];
    float l1 = wr[1] * patch[1];
    float l2 = wr[2] * patch[2];
    float l3 = wr[3] * patch[3];
#pragma unroll
    for (int t = 1; t < 6; ++t) {
        l0 += wr[4 * t + 0] * patch[4 * t + 0];
        l1 += wr[4 * t + 1] * patch[4 * t + 1];
        l2 += wr[4 * t + 2] * patch[4 * t + 2];
        l3 += wr[4 * t + 3] * patch[4 * t + 3];
    }
    float acc = (l0 + l1) + (l2 + l3);
    acc += wr[24] * patch[24];
    return acc > 0.f ? acc : 0.f;
}

// ---------------- weight packing ----------------
__global__ void pack_conv_w(const float* __restrict__ w, uint32_t* __restrict__ wp, int taps) {
    int idx = blockIdx.x * 256 + threadIdx.x;
    if (idx >= 128 * taps) return;
    int oc = idx / taps, t = idx - oc * taps;
    uint32_t words[4] = {0u, 0u, 0u, 0u};
    for (int ic = 0; ic < 128; ++ic) {
        float v = w[(size_t)(oc * 128 + ic) * taps + t];
        if (v > 0.f) words[ic >> 5] |= 1u << (ic & 31);
    }
#pragma unroll
    for (int k = 0; k < 4; ++k) wp[((size_t)t * 128 + oc) * 4 + k] = words[k];
}

__global__ void pack_fc_w(const float* __restrict__ w, uint32_t* __restrict__ wp) {
    int o = blockIdx.x * 256 + threadIdx.x;
    if (o >= 512) return;
    for (int k = 0; k < 64; ++k) {
        uint32_t bits = 0;
        for (int i = 0; i < 32; ++i)
            bits |= (w[(size_t)o * 2048 + k * 32 + i] > 0.f ? 1u : 0u) << i;
        wp[k * 512 + o] = bits;
    }
}

// ---------------- conv1 mean: h staged per 16-channel group, numpy-pairwise ----
// Leaves per channel: offsets {0,96,192,288,392,488,584,680}, lens
// {96,96,96,104,96,96,96,104} (all %8==0). 8 accumulator chains per leaf ->
// lanes; combine via xor-shuffles in exact adjacent-pair order; channel sums
// tree-reduced (128 = 2^7, adjacent pairs == numpy recursion).
__global__ __launch_bounds__(256) void conv1_mean(
    const float* __restrict__ x, const float* __restrict__ w1,
    float* __restrict__ mean1, int* __restrict__ zcnt) {
    __shared__ float img[1024];
    __shared__ float hbuf[16 * 784];
    __shared__ float tree[256];
    int n = blockIdx.x, tid = threadIdx.x;
    for (int i = tid; i < 1024; i += 256) img[i] = x[(size_t)n * 1024 + i];
    __syncthreads();
    int wave = tid >> 6, lane = tid & 63;
    int seg = lane >> 3, k = lane & 7;
    int soff = seg * 96 + (seg >= 4 ? 8 : 0);
    int strips = ((seg & 3) == 3) ? 13 : 12;

    for (int g = 0; g < 8; ++g) {
        // phase A: h for channels [g*16, g*16+16)
        for (int p = tid; p < 784; p += 256) {
            int y = p / 28, xx = p - y * 28;
            float patch[25];
#pragma unroll
            for (int ky = 0; ky < 5; ++ky)
#pragma unroll
                for (int kx = 0; kx < 5; ++kx)
                    patch[ky * 5 + kx] = img[(y + ky) * 32 + xx + kx];
#pragma unroll 2
            for (int cl = 0; cl < 16; ++cl) {
                const float* wr = w1 + (g * 16 + cl) * 25;
                hbuf[cl * 784 + p] = einsum25(patch, wr);
            }
        }
        __syncthreads();
        // phase B: chains -> leaf -> channel sums
        for (int it = 0; it < 4; ++it) {
            int cl = wave * 4 + it;
            const float* hc = &hbuf[cl * 784];
            float r = hc[soff + k];
#pragma unroll
            for (int i = 1; i < 12; ++i) r += hc[soff + 8 * i + k];
            if (strips == 13) r += hc[soff + 96 + k];
            r = r + __shfl_xor(r, 1);
            r = r + __shfl_xor(r, 2);
            r = r + __shfl_xor(r, 4);   // leaf sums
            r = r + __shfl_xor(r, 8);
            r = r + __shfl_xor(r, 16);
            r = r + __shfl_xor(r, 32);  // channel sum
            if (lane == 0) tree[g * 16 + cl] = r;
        }
        __syncthreads();
    }
    // adjacent-pair tree over 128 channel sums (expanding buffer, no races)
    int src = 0, cnt = 128;
    while (cnt > 1) {
        int dst = src + cnt;
        for (int i = tid; i < cnt / 2; i += 256) tree[dst + i] = tree[src + 2 * i] + tree[src + 2 * i + 1];
        __syncthreads();
        src = dst; cnt >>= 1;
    }
    if (tid == 0) { mean1[n] = tree[src] / 100352.0f; zcnt[n] = 0; }
}

// ---------------- conv1 binarize + pack; detect sign(0) ties ----------------
__global__ __launch_bounds__(256) void conv1_bin(
    const float* __restrict__ x, const float* __restrict__ w1,
    const float* __restrict__ mean1, uint32_t* __restrict__ b1p,
    int* __restrict__ zcnt, int* __restrict__ zlist) {
    __shared__ float img[1024];
    int n = blockIdx.x, tid = threadIdx.x;
    for (int i = tid; i < 1024; i += 256) img[i] = x[(size_t)n * 1024 + i];
    __syncthreads();
    float mean = mean1[n];
    for (int p = tid; p < 784; p += 256) {
        int y = p / 28, xx = p - y * 28;
        float patch[25];
#pragma unroll
        for (int ky = 0; ky < 5; ++ky)
#pragma unroll
            for (int kx = 0; kx < 5; ++kx)
                patch[ky * 5 + kx] = img[(y + ky) * 32 + xx + kx];
        uint32_t words[4] = {0u, 0u, 0u, 0u};
#pragma unroll 2
        for (int c = 0; c < 128; ++c) {
            float h = einsum25(patch, w1 + c * 25);
            if (h > mean) words[c >> 5] |= 1u << (c & 31);
            else if (h == mean) {                 // sign(0) = 0 in reference
                int kz = atomicAdd(&zcnt[n], 1);
                if (kz < MAXZ) zlist[n * MAXZ + kz] = p * 128 + c;
            }
        }
#pragma unroll
        for (int k = 0; k < 4; ++k) b1p[((size_t)n * 784 + p) * 4 + k] = words[k];
    }
}

// ---------------- binary conv (xnor-popcount) + optional pool + zero fixup ----
template <int AH, int AW, int KS, int POOL, int OW, int NPOS>
__global__ __launch_bounds__(256) void bconv_kernel(
    const uint32_t* __restrict__ actg, const uint32_t* __restrict__ wp,
    float* __restrict__ rout, const int* __restrict__ zcnt,
    const int* __restrict__ zlist) {
    __shared__ __align__(16) uint32_t act[AH * AW * 4];
    __shared__ __align__(16) uint32_t wsh[KS * KS * 128 * 4];
    int n = blockIdx.x, tid = threadIdx.x;
    const uint32_t* src = actg + (size_t)n * AH * AW * 4;
    for (int i = tid; i < AH * AW * 4; i += 256) act[i] = src[i];
    for (int i = tid; i < KS * KS * 128 * 4; i += 256) wsh[i] = wp[i];
    __syncthreads();
    int oc = tid & 127, s = tid >> 7;
    const int KTOT = 128 * KS * KS;
    int nz = 0, zy[MAXZ], zx[MAXZ], zc[MAXZ];
    if (zcnt) {
        nz = zcnt[n]; nz = nz > MAXZ ? MAXZ : nz;
        for (int i = 0; i < nz; ++i) {
            int e = zlist[n * MAXZ + i];
            int p = e >> 7; zc[i] = e & 127; zy[i] = p / AW; zx[i] = p - zy[i] * AW;
        }
    }
    for (int pp = s; pp < NPOS; pp += 2) {
        int py = pp / OW, px = pp - py * OW;
        int r;
        if (POOL) {
            int cy = py * 2, cx = px * 2;
            int a0 = 0, a1 = 0, a2 = 0, a3 = 0;
#pragma unroll
            for (int ky = 0; ky < KS; ++ky)
#pragma unroll
                for (int kx = 0; kx < KS; ++kx) {
                    uint4 wv = *(const uint4*)&wsh[((ky * KS + kx) * 128 + oc) * 4];
                    const uint32_t* ab = &act[((cy + ky) * AW + cx + kx) * 4];
                    uint4 v0 = *(const uint4*)(ab);
                    uint4 v1 = *(const uint4*)(ab + 4);
                    uint4 v2 = *(const uint4*)(ab + AW * 4);
                    uint4 v3 = *(const uint4*)(ab + AW * 4 + 4);
                    a0 += __popc(v0.x ^ wv.x) + __popc(v0.y ^ wv.y) + __popc(v0.z ^ wv.z) + __popc(v0.w ^ wv.w);
                    a1 += __popc(v1.x ^ wv.x) + __popc(v1.y ^ wv.y) + __popc(v1.z ^ wv.z) + __popc(v1.w ^ wv.w);
                    a2 += __popc(v2.x ^ wv.x) + __popc(v2.y ^ wv.y) + __popc(v2.z ^ wv.z) + __popc(v2.w ^ wv.w);
                    a3 += __popc(v3.x ^ wv.x) + __popc(v3.y ^ wv.y) + __popc(v3.z ^ wv.z) + __popc(v3.w ^ wv.w);
                }
            int m0 = KTOT - 2 * a0, m1 = KTOT - 2 * a1;
            int m2 = KTOT - 2 * a2, m3 = KTOT - 2 * a3;
            if (nz) {
                for (int i = 0; i < nz; ++i) {
#pragma unroll
                    for (int d = 0; d < 4; ++d) {
                        int oy = cy + (d >> 1), ox = cx + (d & 1);
                        int ky = zy[i] - oy, kx = zx[i] - ox;
                        if (ky >= 0 && ky < KS && kx >= 0 && kx < KS) {
                            int wbit = (wsh[((ky * KS + kx) * 128 + oc) * 4 + (zc[i] >> 5)] >> (zc[i] & 31)) & 1;
                            int adj = wbit ? 1 : -1;   // remove spurious (-1)*W contribution
                            if (d == 0) m0 += adj; else if (d == 1) m1 += adj;
                            else if (d == 2) m2 += adj; else m3 += adj;
                        }
                    }
                }
            }
            r = max(max(m0, m1), max(m2, m3));
        } else {
            int a0 = 0;
#pragma unroll
            for (int ky = 0; ky < KS; ++ky)
#pragma unroll
                for (int kx = 0; kx < KS; ++kx) {
                    uint4 wv = *(const uint4*)&wsh[((ky * KS + kx) * 128 + oc) * 4];
                    uint4 v0 = *(const uint4*)&act[((py + ky) * AW + px + kx) * 4];
                    a0 += __popc(v0.x ^ wv.x) + __popc(v0.y ^ wv.y) + __popc(v0.z ^ wv.z) + __popc(v0.w ^ wv.w);
                }
            r = KTOT - 2 * a0;
        }
        r = r > 0 ? r : 0;
        rout[((size_t)n * NPOS + pp) * 128 + oc] = (float)r;  // integer, lossless
    }
}

// ---------------- numpy-pairwise f32 mean for layers 2/3/4 ----------------
template <int NPOS, int NLEAF, int CHUNK, int L0, int L1>
__global__ __launch_bounds__(256) void npmean_kernel(
    const float* __restrict__ rbuf, const float* __restrict__ alpha,
    float* __restrict__ means) {
    __shared__ float ls[2 * NLEAF];
    int n = blockIdx.x, tid = threadIdx.x;
    const int NTOT = NPOS * 128;
    const float* rb = rbuf + (size_t)n * NTOT;
    if (tid < NLEAF) {
        int j0 = CHUNK * (tid >> 1) + ((tid & 1) ? L0 : 0);
        int len = (tid & 1) ? L1 : L0;
        float r[8];
#pragma unroll
        for (int k = 0; k < 8; ++k) {
            int j = j0 + k;
            int c = j / NPOS, p = j - c * NPOS;
            r[k] = mulr(alpha[c], rb[p * 128 + c]);
        }
        int i = 8;
        int lim = len - (len % 8);
        for (; i < lim; i += 8) {
#pragma unroll
            for (int k = 0; k < 8; ++k) {
                int j = j0 + i + k;
                int c = j / NPOS, p = j - c * NPOS;
                r[k] += mulr(alpha[c], rb[p * 128 + c]);
            }
        }
        float res = ((r[0] + r[1]) + (r[2] + r[3])) + ((r[4] + r[5]) + (r[6] + r[7]));
        for (; i < len; ++i) {
            int j = j0 + i;
            int c = j / NPOS, p = j - c * NPOS;
            res += mulr(alpha[c], rb[p * 128 + c]);
        }
        ls[tid] = res;
    }
    __syncthreads();
    int src = 0, cnt = NLEAF;
    while (cnt > 1) {
        int dst = src + cnt;
        for (int i = tid; i < cnt / 2; i += 256) ls[dst + i] = ls[src + 2 * i] + ls[src + 2 * i + 1];
        __syncthreads();
        src = dst; cnt >>= 1;
    }
    if (tid == 0) means[n] = ls[src] / (float)NTOT;
}

// ---------------- binarize (f32 compare, matching refs) ----------------
__global__ void bin_kernel(const float* __restrict__ rbuf, const float* __restrict__ means,
                           const float* __restrict__ alpha,
                           uint32_t* __restrict__ bp, int npos) {
    int idx = blockIdx.x * 256 + threadIdx.x;
    int total = BATCH * npos * 4;
    if (idx >= total) return;
    int n = idx / (npos * 4);
    int w = idx & 3;
    float mean = means[n];
    const float* hb = rbuf + (size_t)idx * 32;
    uint32_t bits = 0;
#pragma unroll
    for (int i = 0; i < 32; ++i) {
        float v = mulr(alpha[w * 32 + i], hb[i]);
        bits |= (v > mean ? 1u : 0u) << i;
    }
    bp[idx] = bits;
}

__global__ void bin4_kernel(const float* __restrict__ r4, const float* __restrict__ means,
                            const float* __restrict__ alpha,
                            uint32_t* __restrict__ bxp) {
    int idx = blockIdx.x * 256 + threadIdx.x;   // 512*64
    if (idx >= BATCH * 64) return;
    int n = idx >> 6, w = idx & 63;
    float mean = means[n];
    uint32_t bits = 0;
#pragma unroll
    for (int i = 0; i < 32; ++i) {
        int f = w * 32 + i;
        int c = f >> 4, sp = f & 15;
        float v = mulr(alpha[c], r4[((size_t)n * 16 + sp) * 128 + c]);
        bits |= (v > mean ? 1u : 0u) << i;
    }
    bxp[idx] = bits;
}

// ---------------- binary FC ----------------
__global__ __launch_bounds__(256) void fc_kernel(
    const uint32_t* __restrict__ bxp, const uint32_t* __restrict__ fcpT,
    const float* __restrict__ bias, const float* __restrict__ alpha,
    float* __restrict__ out) {
    __shared__ uint32_t bxs[64];
    int n = blockIdx.x, tid = threadIdx.x;
    if (tid < 64) bxs[tid] = bxp[n * 64 + tid];
    __syncthreads();
    for (int o = tid; o < 512; o += 256) {
        int acc = 0;
#pragma unroll
        for (int k = 0; k < 64; ++k) acc += __popc(bxs[k] ^ fcpT[k * 512 + o]);
        float dot = (float)(2048 - 2 * acc);
        out[(size_t)n * 512 + o] = (dot + bias[o]) * alpha[o];
    }
}

extern "C" void kernel_launch(void* const* d_in, const int* in_sizes, int n_in,
                              void* d_out, int out_size, void* d_ws, size_t ws_size,
                              hipStream_t stream) {
    const float* x   = (const float*)d_in[0];
    const float* w1  = (const float*)d_in[1];
    const float* w2  = (const float*)d_in[2];
    const float* a2  = (const float*)d_in[3];
    const float* w3  = (const float*)d_in[4];
    const float* a3  = (const float*)d_in[5];
    const float* w4  = (const float*)d_in[6];
    const float* a4  = (const float*)d_in[7];
    const float* wfc = (const float*)d_in[8];
    const float* bfc = (const float*)d_in[9];
    const float* afc = (const float*)d_in[10];
    float* out = (float*)d_out;
    char* ws = (char*)d_ws;

    uint32_t* w2p = (uint32_t*)(ws + OFF_W2P);
    uint32_t* w3p = (uint32_t*)(ws + OFF_W3P);
    uint32_t* w4p = (uint32_t*)(ws + OFF_W4P);
    uint32_t* fcp = (uint32_t*)(ws + OFF_FCP);
    float*    mean1 = (float*)(ws + OFF_STAT);
    float*    mean2 = (float*)(ws + OFF_STAT + 2048);
    float*    mean3 = (float*)(ws + OFF_STAT + 4096);
    float*    mean4 = (float*)(ws + OFF_STAT + 6144);
    int*      zcnt  = (int*)(ws + OFF_STAT + 8192);
    int*      zlist = (int*)(ws + OFF_STAT + 10240);
    uint32_t* b1p = (uint32_t*)(ws + OFF_B1P);
    float*    h2  = (float*)(ws + OFF_H2);
    uint32_t* b2p = (uint32_t*)(ws + OFF_B2P);
    float*    h3  = (float*)(ws + OFF_H3);
    uint32_t* b3p = (uint32_t*)(ws + OFF_B3P);
    float*    h4  = (float*)(ws + OFF_H4);
    uint32_t* bxp = (uint32_t*)(ws + OFF_BXP);

    pack_conv_w<<<(128 * 25 + 255) / 256, 256, 0, stream>>>(w2, w2p, 25);
    pack_conv_w<<<(128 * 9 + 255) / 256, 256, 0, stream>>>(w3, w3p, 9);
    pack_conv_w<<<(128 * 9 + 255) / 256, 256, 0, stream>>>(w4, w4p, 9);
    pack_fc_w<<<2, 256, 0, stream>>>(wfc, fcp);

    conv1_mean<<<BATCH, 256, 0, stream>>>(x, w1, mean1, zcnt);
    conv1_bin<<<BATCH, 256, 0, stream>>>(x, w1, mean1, b1p, zcnt, zlist);

    bconv_kernel<28, 28, 5, 1, 12, 144><<<BATCH, 256, 0, stream>>>(b1p, w2p, h2, zcnt, zlist);
    npmean_kernel<144, 256, 144, 72, 72><<<BATCH, 256, 0, stream>>>(h2, a2, mean2);
    bin_kernel<<<(BATCH * 144 * 4) / 256, 256, 0, stream>>>(h2, mean2, a2, b2p, 144);

    bconv_kernel<12, 12, 3, 0, 10, 100><<<BATCH, 256, 0, stream>>>(b2p, w3p, h3, nullptr, nullptr);
    npmean_kernel<100, 128, 200, 96, 104><<<BATCH, 256, 0, stream>>>(h3, a3, mean3);
    bin_kernel<<<(BATCH * 100 * 4) / 256, 256, 0, stream>>>(h3, mean3, a3, b3p, 100);

    bconv_kernel<10, 10, 3, 1, 4, 16><<<BATCH, 256, 0, stream>>>(b3p, w4p, h4, nullptr, nullptr);
    npmean_kernel<16, 16, 256, 128, 128><<<BATCH, 256, 0, stream>>>(h4, a4, mean4);
    bin4_kernel<<<(BATCH * 64) / 256, 256, 0, stream>>>(h4, mean4, a4, bxp);

    fc_kernel<<<BATCH, 256, 0, stream>>>(bxp, fcp, bfc, afc, out);
}

// Round 10
// 986.013 us; speedup vs baseline: 1.5399x; 1.0496x over previous
//
#include <hip/hip_runtime.h>
#include <stdint.h>

#define BATCH 512
#define MAXZ 3

// ---- workspace layout (bytes) ----
static const size_t OFF_W2P  = 0;          // 25*128*4 u32
static const size_t OFF_W3P  = 51200;
static const size_t OFF_W4P  = 69632;
static const size_t OFF_FCP  = 88064;
static const size_t OFF_STAT = 219136;     // mean1 f32[512]@0; zcnt int[512]@8192; zlist int[512*3]@10240
static const size_t OFF_B1P  = 235520;     // 512*784*16
static const size_t OFF_H2   = 6658048;    // 512*144*128*4 raw counts (float, exact)
static const size_t OFF_B2P  = 44406784;
static const size_t OFF_H3   = 45586432;   // 512*100*128*4
static const size_t OFF_B3P  = 71800832;
static const size_t OFF_H4   = 72620032;   // 512*16*128*4
static const size_t OFF_BXP  = 76814336;
// end ~76.9 MB

// Numerics model (validated r8/r9, absmax=0): conv1 = np.einsum f32 SSE2
// order (separately-rounded mul/add via `fp contract(off)`); means = numpy
// pairwise-f32; sign(0) ties -> zlist fixup in conv2; all binary layers
// exact integer xnor-popcount.

__device__ inline float mulr(float a, float b) {
    float t = a * b;
    asm volatile("" : "+v"(t));
    return t;
}

__device__ inline int popc4(uint4 a, uint4 b) {
    return __popc(a.x ^ b.x) + __popc(a.y ^ b.y) + __popc(a.z ^ b.z) + __popc(a.w ^ b.w);
}

// einsum SSE2-order 25-tap dot + relu, separately-rounded mul/add (no FMA).
__device__ inline float einsum25(const float* __restrict__ patch,
                                 const float* __restrict__ wr) {
#pragma clang fp contract(off)
    float l0 = wr[0] * patch[0];
    float l1 = wr[1] * patch[1];
    float l2 = wr[2] * patch[2];
    float l3 = wr[3] * patch[3];
#pragma unroll
    for (int t = 1; t < 6; ++t) {
        l0 += wr[4 * t + 0] * patch[4 * t + 0];
        l1 += wr[4 * t + 1] * patch[4 * t + 1];
        l2 += wr[4 * t + 2] * patch[4 * t + 2];
        l3 += wr[4 * t + 3] * patch[4 * t + 3];
    }
    float acc = (l0 + l1) + (l2 + l3);
    acc += wr[24] * patch[24];
    return acc > 0.f ? acc : 0.f;
}

// ---------------- weight packing ----------------
__global__ void pack_conv_w(const float* __restrict__ w, uint32_t* __restrict__ wp, int taps) {
    int idx = blockIdx.x * 256 + threadIdx.x;
    if (idx >= 128 * taps) return;
    int oc = idx / taps, t = idx - oc * taps;
    uint32_t words[4] = {0u, 0u, 0u, 0u};
    for (int ic = 0; ic < 128; ++ic) {
        float v = w[(size_t)(oc * 128 + ic) * taps + t];
        if (v > 0.f) words[ic >> 5] |= 1u << (ic & 31);
    }
#pragma unroll
    for (int k = 0; k < 4; ++k) wp[((size_t)t * 128 + oc) * 4 + k] = words[k];
}

__global__ void pack_fc_w(const float* __restrict__ w, uint32_t* __restrict__ wp) {
    int o = blockIdx.x * 256 + threadIdx.x;
    if (o >= 512) return;
    for (int k = 0; k < 64; ++k) {
        uint32_t bits = 0;
        for (int i = 0; i < 32; ++i)
            bits |= (w[(size_t)o * 2048 + k * 32 + i] > 0.f ? 1u : 0u) << i;
        wp[k * 512 + o] = bits;
    }
}

// ---------------- conv1 mean (numpy-pairwise, h staged per 16-ch group) ----
__global__ __launch_bounds__(256) void conv1_mean(
    const float* __restrict__ x, const float* __restrict__ w1,
    float* __restrict__ mean1, int* __restrict__ zcnt) {
    __shared__ float img[1024];
    __shared__ float hbuf[16 * 784];
    __shared__ float tree[256];
    int n = blockIdx.x, tid = threadIdx.x;
    for (int i = tid; i < 1024; i += 256) img[i] = x[(size_t)n * 1024 + i];
    __syncthreads();
    int wave = tid >> 6, lane = tid & 63;
    int seg = lane >> 3, k = lane & 7;
    int soff = seg * 96 + (seg >= 4 ? 8 : 0);
    int strips = ((seg & 3) == 3) ? 13 : 12;

    for (int g = 0; g < 8; ++g) {
        for (int p = tid; p < 784; p += 256) {
            int y = p / 28, xx = p - y * 28;
            float patch[25];
#pragma unroll
            for (int ky = 0; ky < 5; ++ky)
#pragma unroll
                for (int kx = 0; kx < 5; ++kx)
                    patch[ky * 5 + kx] = img[(y + ky) * 32 + xx + kx];
#pragma unroll 2
            for (int cl = 0; cl < 16; ++cl) {
                const float* wr = w1 + (g * 16 + cl) * 25;
                hbuf[cl * 784 + p] = einsum25(patch, wr);
            }
        }
        __syncthreads();
        for (int it = 0; it < 4; ++it) {
            int cl = wave * 4 + it;
            const float* hc = &hbuf[cl * 784];
            float r = hc[soff + k];
#pragma unroll
            for (int i = 1; i < 12; ++i) r += hc[soff + 8 * i + k];
            if (strips == 13) r += hc[soff + 96 + k];
            r = r + __shfl_xor(r, 1);
            r = r + __shfl_xor(r, 2);
            r = r + __shfl_xor(r, 4);
            r = r + __shfl_xor(r, 8);
            r = r + __shfl_xor(r, 16);
            r = r + __shfl_xor(r, 32);
            if (lane == 0) tree[g * 16 + cl] = r;
        }
        __syncthreads();
    }
    int src = 0, cnt = 128;
    while (cnt > 1) {
        int dst = src + cnt;
        for (int i = tid; i < cnt / 2; i += 256) tree[dst + i] = tree[src + 2 * i] + tree[src + 2 * i + 1];
        __syncthreads();
        src = dst; cnt >>= 1;
    }
    if (tid == 0) { mean1[n] = tree[src] / 100352.0f; zcnt[n] = 0; }
}

// ---------------- conv1 binarize + pack; detect sign(0) ties ----------------
__global__ __launch_bounds__(256) void conv1_bin(
    const float* __restrict__ x, const float* __restrict__ w1,
    const float* __restrict__ mean1, uint32_t* __restrict__ b1p,
    int* __restrict__ zcnt, int* __restrict__ zlist) {
    __shared__ float img[1024];
    int n = blockIdx.x, tid = threadIdx.x;
    for (int i = tid; i < 1024; i += 256) img[i] = x[(size_t)n * 1024 + i];
    __syncthreads();
    float mean = mean1[n];
    for (int p = tid; p < 784; p += 256) {
        int y = p / 28, xx = p - y * 28;
        float patch[25];
#pragma unroll
        for (int ky = 0; ky < 5; ++ky)
#pragma unroll
            for (int kx = 0; kx < 5; ++kx)
                patch[ky * 5 + kx] = img[(y + ky) * 32 + xx + kx];
        uint32_t words[4] = {0u, 0u, 0u, 0u};
#pragma unroll 2
        for (int c = 0; c < 128; ++c) {
            float h = einsum25(patch, w1 + c * 25);
            if (h > mean) words[c >> 5] |= 1u << (c & 31);
            else if (h == mean) {
                int kz = atomicAdd(&zcnt[n], 1);
                if (kz < MAXZ) zlist[n * MAXZ + kz] = p * 128 + c;
            }
        }
#pragma unroll
        for (int k = 0; k < 4; ++k) b1p[((size_t)n * 784 + p) * 4 + k] = words[k];
    }
}

// ---------------- bconv2: 28x28 -> 5x5 conv -> pool -> 12x12 ----------------
// weights in VGPRs (25 uint4/thread, lane=oc); act rows read once per row.
// grid: 4 blocks/sample, 36 pooled positions each.
__global__ __launch_bounds__(256) void bconv2_kernel(
    const uint32_t* __restrict__ actg, const uint32_t* __restrict__ wp,
    float* __restrict__ rout, const int* __restrict__ zcnt,
    const int* __restrict__ zlist) {
    __shared__ __align__(16) uint32_t act[28 * 28 * 4];
    int blk = blockIdx.x;
    int n = blk >> 2, q = blk & 3;
    int tid = threadIdx.x;
    const uint32_t* src = actg + (size_t)n * 3136;
    for (int i = tid; i < 3136; i += 256) act[i] = src[i];
    int oc = tid & 127, s = tid >> 7;
    uint4 wreg[25];
#pragma unroll
    for (int t = 0; t < 25; ++t) wreg[t] = *(const uint4*)&wp[(t * 128 + oc) * 4];
    int nz = zcnt[n]; nz = nz > MAXZ ? MAXZ : nz;
    int zy[MAXZ], zx[MAXZ], zc[MAXZ];
    for (int i = 0; i < nz; ++i) {
        int e = zlist[n * MAXZ + i];
        int p = e >> 7; zc[i] = e & 127; zy[i] = p / 28; zx[i] = p - zy[i] * 28;
    }
    __syncthreads();
    for (int pp = q * 36 + s; pp < (q + 1) * 36; pp += 2) {
        int py = pp / 12, px = pp - py * 12;
        int cy = py * 2, cx = px * 2;
        int a00 = 0, a01 = 0, a10 = 0, a11 = 0;
#pragma unroll
        for (int rr = 0; rr < 6; ++rr) {
            uint4 rb[6];
#pragma unroll
            for (int j = 0; j < 6; ++j) rb[j] = *(const uint4*)&act[((cy + rr) * 28 + cx + j) * 4];
#pragma unroll
            for (int dy = 0; dy < 2; ++dy) {
                if (rr - dy < 0 || rr - dy > 4) continue;
                int ky = rr - dy;
#pragma unroll
                for (int kx = 0; kx < 5; ++kx) {
                    uint4 wv = wreg[ky * 5 + kx];
                    int p0 = popc4(rb[kx], wv);
                    int p1 = popc4(rb[kx + 1], wv);
                    if (dy == 0) { a00 += p0; a01 += p1; } else { a10 += p0; a11 += p1; }
                }
            }
        }
        int m00 = 3200 - 2 * a00, m01 = 3200 - 2 * a01;
        int m10 = 3200 - 2 * a10, m11 = 3200 - 2 * a11;
        for (int i = 0; i < nz; ++i) {
#pragma unroll
            for (int d = 0; d < 4; ++d) {
                int ky = zy[i] - (cy + (d >> 1)), kx = zx[i] - (cx + (d & 1));
                if (ky >= 0 && ky < 5 && kx >= 0 && kx < 5) {
                    uint4 wv = wreg[ky * 5 + kx];
                    int wsel = zc[i] >> 5;
                    uint32_t word = wsel == 0 ? wv.x : (wsel == 1 ? wv.y : (wsel == 2 ? wv.z : wv.w));
                    int adj = ((word >> (zc[i] & 31)) & 1) ? 1 : -1;
                    if (d == 0) m00 += adj; else if (d == 1) m01 += adj;
                    else if (d == 2) m10 += adj; else m11 += adj;
                }
            }
        }
        int r = max(max(m00, m01), max(m10, m11));
        r = r > 0 ? r : 0;
        rout[((size_t)n * 144 + pp) * 128 + oc] = (float)r;
    }
}

// ---------------- bconv3: 12x12 -> 3x3 conv -> 10x10 ----------------
__global__ __launch_bounds__(256) void bconv3_kernel(
    const uint32_t* __restrict__ actg, const uint32_t* __restrict__ wp,
    float* __restrict__ rout) {
    __shared__ __align__(16) uint32_t act[12 * 12 * 4];
    int blk = blockIdx.x;
    int n = blk >> 1, q = blk & 1;
    int tid = threadIdx.x;
    const uint32_t* src = actg + (size_t)n * 576;
    for (int i = tid; i < 576; i += 256) act[i] = src[i];
    int oc = tid & 127, s = tid >> 7;
    uint4 wreg[9];
#pragma unroll
    for (int t = 0; t < 9; ++t) wreg[t] = *(const uint4*)&wp[(t * 128 + oc) * 4];
    __syncthreads();
    for (int pp = q * 50 + s; pp < (q + 1) * 50; pp += 2) {
        int py = pp / 10, px = pp - py * 10;
        int acc = 0;
#pragma unroll
        for (int rr = 0; rr < 3; ++rr) {
#pragma unroll
            for (int kx = 0; kx < 3; ++kx) {
                uint4 v = *(const uint4*)&act[((py + rr) * 12 + px + kx) * 4];
                acc += popc4(v, wreg[rr * 3 + kx]);
            }
        }
        int r = 1152 - 2 * acc;
        r = r > 0 ? r : 0;
        rout[((size_t)n * 100 + pp) * 128 + oc] = (float)r;
    }
}

// ---------------- bconv4: 10x10 -> 3x3 conv -> pool -> 4x4 ----------------
__global__ __launch_bounds__(256) void bconv4_kernel(
    const uint32_t* __restrict__ actg, const uint32_t* __restrict__ wp,
    float* __restrict__ rout) {
    __shared__ __align__(16) uint32_t act[10 * 10 * 4];
    int n = blockIdx.x, tid = threadIdx.x;
    const uint32_t* src = actg + (size_t)n * 400;
    for (int i = tid; i < 400; i += 256) act[i] = src[i];
    int oc = tid & 127, s = tid >> 7;
    uint4 wreg[9];
#pragma unroll
    for (int t = 0; t < 9; ++t) wreg[t] = *(const uint4*)&wp[(t * 128 + oc) * 4];
    __syncthreads();
    for (int pp = s; pp < 16; pp += 2) {
        int py = pp >> 2, px = pp & 3;
        int cy = py * 2, cx = px * 2;
        int a00 = 0, a01 = 0, a10 = 0, a11 = 0;
#pragma unroll
        for (int rr = 0; rr < 4; ++rr) {
            uint4 rb[4];
#pragma unroll
            for (int j = 0; j < 4; ++j) rb[j] = *(const uint4*)&act[((cy + rr) * 10 + cx + j) * 4];
#pragma unroll
            for (int dy = 0; dy < 2; ++dy) {
                if (rr - dy < 0 || rr - dy > 2) continue;
                int ky = rr - dy;
#pragma unroll
                for (int kx = 0; kx < 3; ++kx) {
                    uint4 wv = wreg[ky * 3 + kx];
                    int p0 = popc4(rb[kx], wv);
                    int p1 = popc4(rb[kx + 1], wv);
                    if (dy == 0) { a00 += p0; a01 += p1; } else { a10 += p0; a11 += p1; }
                }
            }
        }
        int m00 = 1152 - 2 * a00, m01 = 1152 - 2 * a01;
        int m10 = 1152 - 2 * a10, m11 = 1152 - 2 * a11;
        int r = max(max(m00, m01), max(m10, m11));
        r = r > 0 ? r : 0;
        rout[((size_t)n * 16 + pp) * 128 + oc] = (float)r;
    }
}

// ---------------- fused numpy-pairwise mean + binarize ----------------
// MODE 0: NHWC word binarize (layers 2,3). MODE 1: NCHW-flatten (layer 4).
template <int NPOS, int NLEAF, int CHUNK, int L0, int L1, int MODE>
__global__ __launch_bounds__(256) void npmean_bin_kernel(
    const float* __restrict__ rbuf, const float* __restrict__ alpha,
    uint32_t* __restrict__ bp) {
    __shared__ float ls[2 * NLEAF];
    int n = blockIdx.x, tid = threadIdx.x;
    const int NTOT = NPOS * 128;
    const float* rb = rbuf + (size_t)n * NTOT;
    if (tid < NLEAF) {
        int j0 = CHUNK * (tid >> 1) + ((tid & 1) ? L0 : 0);
        int len = (tid & 1) ? L1 : L0;
        float r[8];
#pragma unroll
        for (int k = 0; k < 8; ++k) {
            int j = j0 + k;
            int c = j / NPOS, p = j - c * NPOS;
            r[k] = mulr(alpha[c], rb[p * 128 + c]);
        }
        int i = 8;
        int lim = len - (len % 8);
        for (; i < lim; i += 8) {
#pragma unroll
            for (int k = 0; k < 8; ++k) {
                int j = j0 + i + k;
                int c = j / NPOS, p = j - c * NPOS;
                r[k] += mulr(alpha[c], rb[p * 128 + c]);
            }
        }
        float res = ((r[0] + r[1]) + (r[2] + r[3])) + ((r[4] + r[5]) + (r[6] + r[7]));
        for (; i < len; ++i) {
            int j = j0 + i;
            int c = j / NPOS, p = j - c * NPOS;
            res += mulr(alpha[c], rb[p * 128 + c]);
        }
        ls[tid] = res;
    }
    __syncthreads();
    int src = 0, cnt = NLEAF;
    while (cnt > 1) {
        int dst = src + cnt;
        for (int i = tid; i < cnt / 2; i += 256) ls[dst + i] = ls[src + 2 * i] + ls[src + 2 * i + 1];
        __syncthreads();
        src = dst; cnt >>= 1;
    }
    float mean = ls[src] / (float)NTOT;
    if (MODE == 0) {
        for (int widx = tid; widx < NPOS * 4; widx += 256) {
            int w = widx & 3;
            const float* hb = rb + (size_t)widx * 32;
            uint32_t bits = 0;
#pragma unroll
            for (int i = 0; i < 32; ++i) {
                float v = mulr(alpha[w * 32 + i], hb[i]);
                bits |= (v > mean ? 1u : 0u) << i;
            }
            bp[(size_t)n * NPOS * 4 + widx] = bits;
        }
    } else {
        if (tid < 64) {
            int w = tid;
            uint32_t bits = 0;
#pragma unroll
            for (int i = 0; i < 32; ++i) {
                int f = w * 32 + i;
                int c = f >> 4, sp = f & 15;
                float v = mulr(alpha[c], rb[sp * 128 + c]);
                bits |= (v > mean ? 1u : 0u) << i;
            }
            bp[n * 64 + w] = bits;
        }
    }
}

// ---------------- binary FC ----------------
__global__ __launch_bounds__(256) void fc_kernel(
    const uint32_t* __restrict__ bxp, const uint32_t* __restrict__ fcpT,
    const float* __restrict__ bias, const float* __restrict__ alpha,
    float* __restrict__ out) {
    __shared__ uint32_t bxs[64];
    int n = blockIdx.x, tid = threadIdx.x;
    if (tid < 64) bxs[tid] = bxp[n * 64 + tid];
    __syncthreads();
    for (int o = tid; o < 512; o += 256) {
        int acc = 0;
#pragma unroll
        for (int k = 0; k < 64; ++k) acc += __popc(bxs[k] ^ fcpT[k * 512 + o]);
        float dot = (float)(2048 - 2 * acc);
        out[(size_t)n * 512 + o] = (dot + bias[o]) * alpha[o];
    }
}

extern "C" void kernel_launch(void* const* d_in, const int* in_sizes, int n_in,
                              void* d_out, int out_size, void* d_ws, size_t ws_size,
                              hipStream_t stream) {
    const float* x   = (const float*)d_in[0];
    const float* w1  = (const float*)d_in[1];
    const float* w2  = (const float*)d_in[2];
    const float* a2  = (const float*)d_in[3];
    const float* w3  = (const float*)d_in[4];
    const float* a3  = (const float*)d_in[5];
    const float* w4  = (const float*)d_in[6];
    const float* a4  = (const float*)d_in[7];
    const float* wfc = (const float*)d_in[8];
    const float* bfc = (const float*)d_in[9];
    const float* afc = (const float*)d_in[10];
    float* out = (float*)d_out;
    char* ws = (char*)d_ws;

    uint32_t* w2p = (uint32_t*)(ws + OFF_W2P);
    uint32_t* w3p = (uint32_t*)(ws + OFF_W3P);
    uint32_t* w4p = (uint32_t*)(ws + OFF_W4P);
    uint32_t* fcp = (uint32_t*)(ws + OFF_FCP);
    float*    mean1 = (float*)(ws + OFF_STAT);
    int*      zcnt  = (int*)(ws + OFF_STAT + 8192);
    int*      zlist = (int*)(ws + OFF_STAT + 10240);
    uint32_t* b1p = (uint32_t*)(ws + OFF_B1P);
    float*    h2  = (float*)(ws + OFF_H2);
    uint32_t* b2p = (uint32_t*)(ws + OFF_B2P);
    float*    h3  = (float*)(ws + OFF_H3);
    uint32_t* b3p = (uint32_t*)(ws + OFF_B3P);
    float*    h4  = (float*)(ws + OFF_H4);
    uint32_t* bxp = (uint32_t*)(ws + OFF_BXP);

    pack_conv_w<<<(128 * 25 + 255) / 256, 256, 0, stream>>>(w2, w2p, 25);
    pack_conv_w<<<(128 * 9 + 255) / 256, 256, 0, stream>>>(w3, w3p, 9);
    pack_conv_w<<<(128 * 9 + 255) / 256, 256, 0, stream>>>(w4, w4p, 9);
    pack_fc_w<<<2, 256, 0, stream>>>(wfc, fcp);

    conv1_mean<<<BATCH, 256, 0, stream>>>(x, w1, mean1, zcnt);
    conv1_bin<<<BATCH, 256, 0, stream>>>(x, w1, mean1, b1p, zcnt, zlist);

    bconv2_kernel<<<BATCH * 4, 256, 0, stream>>>(b1p, w2p, h2, zcnt, zlist);
    npmean_bin_kernel<144, 256, 144, 72, 72, 0><<<BATCH, 256, 0, stream>>>(h2, a2, b2p);

    bconv3_kernel<<<BATCH * 2, 256, 0, stream>>>(b2p, w3p, h3);
    npmean_bin_kernel<100, 128, 200, 96, 104, 0><<<BATCH, 256, 0, stream>>>(h3, a3, b3p);

    bconv4_kernel<<<BATCH, 256, 0, stream>>>(b3p, w4p, h4);
    npmean_bin_kernel<16, 16, 256, 128, 128, 1><<<BATCH, 256, 0, stream>>>(h4, a4, bxp);

    fc_kernel<<<BATCH, 256, 0, stream>>>(bxp, fcp, bfc, afc, out);
}